// Round 1
// baseline (93.971 us; speedup 1.0000x reference)
//
#include <hip/hip_runtime.h>
#include <float.h>

// Chamfer distance, B=8, N1=N2=4096, 3-D fp32 points.
// dist(a,b) = |a|^2 + |b|^2 - 2 a.b ; min over the other set, both directions.
// Inner loop: 3 fma + 1 min per pair (|a|^2 added after the min-scan).

#define NBATCH 8
#define NPTS   4096
#define NCHUNK 16
#define CHUNK  (NPTS / NCHUNK)   // 256 B-points staged in LDS per block
#define BLK    256
#define PTS    4                 // A-points per thread
#define ATILE  (BLK * PTS)       // 1024 A-points per block
#define NATILE (NPTS / ATILE)    // 4 a-tiles per batch

__global__ __launch_bounds__(BLK)
void chamfer_min_kernel(const float* __restrict__ p1,
                        const float* __restrict__ p2,
                        unsigned int* __restrict__ mins /* [2][8][4096] uint bits */)
{
    __shared__ float4 sB[CHUNK];

    // blockIdx.x = dir*(8*NATILE*NCHUNK) + b*(NATILE*NCHUNK) + atile*NCHUNK + chunk
    int bid   = blockIdx.x;
    int chunk = bid & (NCHUNK - 1);  bid >>= 4;   // NCHUNK=16
    int atile = bid & (NATILE - 1);  bid >>= 2;   // NATILE=4
    int b     = bid & (NBATCH - 1);  bid >>= 3;   // NBATCH=8
    int dir   = bid;                              // 0 or 1

    const float* A    = dir ? p2 : p1;
    const float* Bpts = dir ? p1 : p2;
    int tid = threadIdx.x;

    // Stage B chunk into LDS as {x,y,z,|b|^2}.
    {
        int j = chunk * CHUNK + tid;
        const float* src = Bpts + ((size_t)b * NPTS + j) * 3;
        float x = src[0], y = src[1], z = src[2];
        sB[tid] = make_float4(x, y, z, x * x + y * y + z * z);
    }
    __syncthreads();

    // Load PTS A-points per thread; pre-scale by -2.
    float m2x[PTS], m2y[PTS], m2z[PTS], n1[PTS], best[PTS];
    int abase = atile * ATILE;
#pragma unroll
    for (int k = 0; k < PTS; ++k) {
        int ai = abase + tid + k * BLK;
        const float* src = A + ((size_t)b * NPTS + ai) * 3;
        float x = src[0], y = src[1], z = src[2];
        m2x[k] = -2.0f * x;
        m2y[k] = -2.0f * y;
        m2z[k] = -2.0f * z;
        n1[k]  = x * x + y * y + z * z;
        best[k] = FLT_MAX;
    }

    // Min-scan over the staged B chunk. Broadcast ds_read_b128 per j,
    // amortized over 4 A-points (16 VALU per LDS instr).
#pragma unroll 4
    for (int j = 0; j < CHUNK; ++j) {
        float4 q = sB[j];
#pragma unroll
        for (int k = 0; k < PTS; ++k) {
            float t = fmaf(m2x[k], q.x, q.w);
            t = fmaf(m2y[k], q.y, t);
            t = fmaf(m2z[k], q.z, t);
            best[k] = fminf(best[k], t);
        }
    }

    // Publish per-A-point chunk-min via uint atomicMin (valid for d >= 0).
    unsigned int* marr = mins + ((size_t)dir * NBATCH + b) * NPTS + abase + tid;
#pragma unroll
    for (int k = 0; k < PTS; ++k) {
        float d = fmaxf(best[k] + n1[k], 0.0f);
        atomicMin(&marr[k * BLK], __float_as_uint(d));
    }
}

__global__ __launch_bounds__(1024)
void chamfer_reduce_kernel(const float* __restrict__ mins, float* __restrict__ out)
{
    // Sum 2*8*4096 = 65536 min-distances; loss = sum / (8*4096).
    __shared__ float wave_sums[16];
    float s = 0.0f;
    for (int i = threadIdx.x; i < 2 * NBATCH * NPTS; i += 1024)
        s += mins[i];
#pragma unroll
    for (int off = 32; off > 0; off >>= 1)
        s += __shfl_down(s, off, 64);
    int wave = threadIdx.x >> 6;
    if ((threadIdx.x & 63) == 0) wave_sums[wave] = s;
    __syncthreads();
    if (threadIdx.x < 16) {
        s = wave_sums[threadIdx.x];
#pragma unroll
        for (int off = 8; off > 0; off >>= 1)
            s += __shfl_down(s, off, 16);
        if (threadIdx.x == 0) out[0] = s / (float)(NBATCH * NPTS);
    }
}

extern "C" void kernel_launch(void* const* d_in, const int* in_sizes, int n_in,
                              void* d_out, int out_size, void* d_ws, size_t ws_size,
                              hipStream_t stream) {
    const float* p1 = (const float*)d_in[0];
    const float* p2 = (const float*)d_in[1];
    float* out = (float*)d_out;
    unsigned int* mins = (unsigned int*)d_ws;

    // Init mins to 0xFFFFFFFF (uint max; > any positive float bit pattern).
    hipMemsetAsync(d_ws, 0xFF, (size_t)2 * NBATCH * NPTS * sizeof(unsigned int), stream);

    int nblocks = 2 * NBATCH * NATILE * NCHUNK;  // 1024
    chamfer_min_kernel<<<nblocks, BLK, 0, stream>>>(p1, p2, mins);
    chamfer_reduce_kernel<<<1, 1024, 0, stream>>>((const float*)d_ws, out);
}

// Round 2
// 81.091 us; speedup vs baseline: 1.1588x; 1.1588x over previous
//
#include <hip/hip_runtime.h>
#include <float.h>

// Chamfer distance, B=8, N1=N2=4096, 3-D fp32 points.
// dist(a,b) = |a|^2 + |b|^2 - 2 a.b ; min over the other set, both directions.
// Packed dual-FP32 (v_pk_fma_f32) inner loop: per 2 B-points x 1 A-point:
// 3 pk_fma + 2 v_min = 2.5 VALU instr/pair (vs 4 scalar).

typedef float v2f __attribute__((ext_vector_type(2)));

#define NBATCH 8
#define NPTS   4096
#define BLK    256
#define PTS    16                 // A-points per thread
#define NCHUNK 32
#define CHUNK  (NPTS / NCHUNK)    // 128 B-points staged per block
#define PAIRS  (CHUNK / 2)        // 64 packed pairs

__global__ __launch_bounds__(BLK)
void chamfer_min_kernel(const float* __restrict__ p1,
                        const float* __restrict__ p2,
                        unsigned int* __restrict__ mins /* [2][8][4096] uint bits */)
{
    // Packed-pair B staging: sXY[p] = {x0,x1,y0,y1}, sZW[p] = {z0,z1,w0,w1}
    // (w = |b|^2). float2 slices of these quads are register-adjacent.
    __shared__ float4 sXY[PAIRS];
    __shared__ float4 sZW[PAIRS];

    int bid   = blockIdx.x;
    int chunk = bid & (NCHUNK - 1);  bid >>= 5;   // 32 chunks
    int b     = bid & (NBATCH - 1);  bid >>= 3;   // 8 batches
    int dir   = bid;                              // 0 or 1

    const float* A    = dir ? p2 : p1;
    const float* Bpts = dir ? p1 : p2;
    int tid = threadIdx.x;

    if (tid < PAIRS) {
        const float* s = Bpts + ((size_t)b * NPTS + chunk * CHUNK + 2 * tid) * 3;
        float x0 = s[0], y0 = s[1], z0 = s[2];
        float x1 = s[3], y1 = s[4], z1 = s[5];
        sXY[tid] = make_float4(x0, x1, y0, y1);
        sZW[tid] = make_float4(z0, z1,
                               x0 * x0 + y0 * y0 + z0 * z0,
                               x1 * x1 + y1 * y1 + z1 * z1);
    }

    // Per-thread A-points, pre-scaled by -2, duplicated into packed pairs.
    v2f  m2x[PTS], m2y[PTS], m2z[PTS];
    float n1[PTS], bestE[PTS], bestO[PTS];
#pragma unroll
    for (int k = 0; k < PTS; ++k) {
        const float* s = A + ((size_t)b * NPTS + tid + k * BLK) * 3;
        float x = s[0], y = s[1], z = s[2];
        float mx = -2.0f * x, my = -2.0f * y, mz = -2.0f * z;
        m2x[k] = (v2f){mx, mx};
        m2y[k] = (v2f){my, my};
        m2z[k] = (v2f){mz, mz};
        n1[k]  = x * x + y * y + z * z;
        bestE[k] = FLT_MAX;
        bestO[k] = FLT_MAX;
    }
    __syncthreads();

    // Min-scan: per packed B-pair, per A-point: 3 pk_fma + 2 min.
#pragma unroll 2
    for (int p = 0; p < PAIRS; ++p) {
        float4 xy = sXY[p];
        float4 zw = sZW[p];
        v2f qx = (v2f){xy.x, xy.y};
        v2f qy = (v2f){xy.z, xy.w};
        v2f qz = (v2f){zw.x, zw.y};
        v2f qw = (v2f){zw.z, zw.w};
#pragma unroll
        for (int k = 0; k < PTS; ++k) {
            v2f t = __builtin_elementwise_fma(m2x[k], qx, qw);
            t = __builtin_elementwise_fma(m2y[k], qy, t);
            t = __builtin_elementwise_fma(m2z[k], qz, t);
            bestE[k] = fminf(bestE[k], t.x);
            bestO[k] = fminf(bestO[k], t.y);
        }
    }

    // Publish per-A-point chunk-min via uint atomicMin (valid for d >= 0).
    unsigned int* marr = mins + ((size_t)dir * NBATCH + b) * NPTS + tid;
#pragma unroll
    for (int k = 0; k < PTS; ++k) {
        float d = fmaxf(fminf(bestE[k], bestO[k]) + n1[k], 0.0f);
        atomicMin(&marr[k * BLK], __float_as_uint(d));
    }
}

__global__ __launch_bounds__(1024)
void chamfer_reduce_kernel(const float* __restrict__ mins, float* __restrict__ out)
{
    // Sum 2*8*4096 = 65536 min-distances; loss = sum / (8*4096).
    __shared__ float wave_sums[16];
    const float4* m4 = (const float4*)mins;
    float s = 0.0f;
#pragma unroll
    for (int i = 0; i < 16; ++i) {
        float4 v = m4[threadIdx.x + i * 1024];
        s += (v.x + v.y) + (v.z + v.w);
    }
#pragma unroll
    for (int off = 32; off > 0; off >>= 1)
        s += __shfl_down(s, off, 64);
    int wave = threadIdx.x >> 6;
    if ((threadIdx.x & 63) == 0) wave_sums[wave] = s;
    __syncthreads();
    if (threadIdx.x < 16) {
        s = wave_sums[threadIdx.x];
#pragma unroll
        for (int off = 8; off > 0; off >>= 1)
            s += __shfl_down(s, off, 16);
        if (threadIdx.x == 0) out[0] = s / (float)(NBATCH * NPTS);
    }
}

extern "C" void kernel_launch(void* const* d_in, const int* in_sizes, int n_in,
                              void* d_out, int out_size, void* d_ws, size_t ws_size,
                              hipStream_t stream) {
    const float* p1 = (const float*)d_in[0];
    const float* p2 = (const float*)d_in[1];
    float* out = (float*)d_out;
    unsigned int* mins = (unsigned int*)d_ws;

    // Init mins to 0xFFFFFFFF (uint max; > any positive float bit pattern).
    hipMemsetAsync(d_ws, 0xFF, (size_t)2 * NBATCH * NPTS * sizeof(unsigned int), stream);

    int nblocks = 2 * NBATCH * NCHUNK;  // 512
    chamfer_min_kernel<<<nblocks, BLK, 0, stream>>>(p1, p2, mins);
    chamfer_reduce_kernel<<<1, 1024, 0, stream>>>((const float*)d_ws, out);
}